// Round 1
// baseline (396.331 us; speedup 1.0000x reference)
//
#include <hip/hip_runtime.h>

#define B_  2
#define L_  2048
#define D_  2048
#define H_  16
#define DH_ 128
#define K_  2048
#define M_  4096

typedef __attribute__((ext_vector_type(8))) short bf16x8;
typedef __attribute__((ext_vector_type(4))) float f32x4;
typedef __attribute__((ext_vector_type(4))) float float4v;
typedef __attribute__((ext_vector_type(8))) unsigned short u16x8;

__device__ __forceinline__ unsigned short f2bf(float f) {
  unsigned u = __builtin_bit_cast(unsigned, f);
  u += 0x7fffu + ((u >> 16) & 1u);
  return (unsigned short)(u >> 16);
}

typedef __attribute__((address_space(3))) unsigned int lds_uint;
typedef __attribute__((address_space(1))) const unsigned int glob_uint;
__device__ __forceinline__ void gld16(const void* g, void* l) {
  __builtin_amdgcn_global_load_lds((glob_uint*)g, (lds_uint*)l, 16, 0, 0);
}

// ---------------- weight f32 -> bf16 prepass ----------------
__global__ void cvt_w(const float* __restrict__ wq, const float* __restrict__ wk,
                      const float* __restrict__ wv, const float* __restrict__ wo,
                      unsigned short* __restrict__ outb) {
  const int z = blockIdx.z;
  const float* src = (z == 0) ? wq : (z == 1) ? wk : (z == 2) ? wv : wo;
  unsigned short* dst = outb + (size_t)z * ((size_t)D_ * D_);
  size_t i = ((size_t)blockIdx.x * 256 + threadIdx.x) * 8;
  float4v x0 = *(const float4v*)(src + i);
  float4v x1 = *(const float4v*)(src + i + 4);
  u16x8 p;
  p[0]=f2bf(x0[0]); p[1]=f2bf(x0[1]); p[2]=f2bf(x0[2]); p[3]=f2bf(x0[3]);
  p[4]=f2bf(x1[0]); p[5]=f2bf(x1[1]); p[6]=f2bf(x1[2]); p[7]=f2bf(x1[3]);
  *(u16x8*)(dst + i) = p;
}

// ---------------- fused QKV projection GEMM ----------------
// C[M,N] = A_f32[M,K] * W_bf16[N,K]^T ; z=0 -> Qh[B,H,L,DH], z=1 -> Kh, z=2 -> Vt[B,H,DH,L]
__global__ __launch_bounds__(256, 2) void proj_gemm(
    const float* __restrict__ q, const float* __restrict__ k, const float* __restrict__ v,
    const unsigned short* __restrict__ wqb, const unsigned short* __restrict__ wkb,
    const unsigned short* __restrict__ wvb,
    unsigned short* __restrict__ Qh, unsigned short* __restrict__ Kh,
    unsigned short* __restrict__ Vt) {
  __shared__ unsigned short smem[128 * 136];  // staging: As[128][64] + Bs[128][64]; epi: T[128][136]
  unsigned short* As = smem;
  unsigned short* Bs = smem + 128 * 64;

  const int z = blockIdx.z;
  const float* A = (z == 0) ? q : (z == 1) ? k : v;
  const unsigned short* W = (z == 0) ? wqb : (z == 1) ? wkb : wvb;

  const int tid = threadIdx.x;
  const int wave = tid >> 6, lane = tid & 63;
  const int wr = wave >> 1, wc = wave & 1;
  const int bm0 = blockIdx.x * 128;
  const int bn0 = blockIdx.y * 128;
  const int l15 = lane & 15, l4 = lane >> 4;

  f32x4 acc[4][4];
#pragma unroll
  for (int m = 0; m < 4; m++)
#pragma unroll
    for (int n = 0; n < 4; n++) { f32x4 zz = {0.f, 0.f, 0.f, 0.f}; acc[m][n] = zz; }

  for (int k0 = 0; k0 < K_; k0 += 64) {
    // B tile via async global->LDS (bf16 weights), linear layout
#pragma unroll
    for (int it = 0; it < 4; ++it) {
      const int base = it * 256 + wave * 64;
      const int ch = base + lane;
      const int r = ch >> 3, c = ch & 7;
      gld16(W + (size_t)(bn0 + r) * K_ + (k0 + c * 8), Bs + base * 8);
    }
    // A tile: f32 -> bf16 reg staging
#pragma unroll
    for (int it = 0; it < 4; ++it) {
      const int ch = it * 256 + tid;
      const int r = ch >> 3, c = ch & 7;
      const float* g = A + (size_t)(bm0 + r) * K_ + (k0 + c * 8);
      float4v x0 = *(const float4v*)g;
      float4v x1 = *(const float4v*)(g + 4);
      u16x8 p;
      p[0]=f2bf(x0[0]); p[1]=f2bf(x0[1]); p[2]=f2bf(x0[2]); p[3]=f2bf(x0[3]);
      p[4]=f2bf(x1[0]); p[5]=f2bf(x1[1]); p[6]=f2bf(x1[2]); p[7]=f2bf(x1[3]);
      *(u16x8*)&As[ch * 8] = p;
    }
    __syncthreads();
#pragma unroll
    for (int ks = 0; ks < 2; ++ks) {
      const int kc = ks * 32 + l4 * 8;
      bf16x8 af[4], bfr[4];
#pragma unroll
      for (int m = 0; m < 4; m++) af[m] = *(const bf16x8*)&As[(wr * 64 + m * 16 + l15) * 64 + kc];
#pragma unroll
      for (int n = 0; n < 4; n++) bfr[n] = *(const bf16x8*)&Bs[(wc * 64 + n * 16 + l15) * 64 + kc];
#pragma unroll
      for (int m = 0; m < 4; m++)
#pragma unroll
        for (int n = 0; n < 4; n++)
          acc[m][n] = __builtin_amdgcn_mfma_f32_16x16x32_bf16(af[m], bfr[n], acc[m][n], 0, 0, 0);
    }
    __syncthreads();
  }

  if (z < 2) {
    unsigned short* O = (z == 0) ? Qh : Kh;
#pragma unroll
    for (int m = 0; m < 4; m++) {
      const int rr = bm0 + wr * 64 + m * 16 + l4 * 4;
#pragma unroll
      for (int n = 0; n < 4; n++) {
        const int cc = bn0 + wc * 64 + n * 16 + l15;
        const int h = cc >> 7, dh = cc & 127;
#pragma unroll
        for (int j = 0; j < 4; j++) {
          const int r2 = rr + j;
          const int b = r2 >> 11, lr = r2 & 2047;
          O[((size_t)(b * H_ + h) * L_ + lr) * DH_ + dh] = f2bf(acc[m][n][j]);
        }
      }
    }
  } else {
    // V: transpose through LDS, write Vt[B,H,DH,L] coalesced
    __syncthreads();
    unsigned short* T = smem;  // [128][136]
#pragma unroll
    for (int m = 0; m < 4; m++)
#pragma unroll
      for (int n = 0; n < 4; n++) {
        const int cl = wc * 64 + n * 16 + l15;
        const int rl = wr * 64 + m * 16 + l4 * 4;
#pragma unroll
        for (int j = 0; j < 4; j++) T[cl * 136 + rl + j] = f2bf(acc[m][n][j]);
      }
    __syncthreads();
    const int b = bm0 >> 11, lbase = bm0 & 2047;
    const int hb = bn0 >> 7;
#pragma unroll
    for (int it = 0; it < 8; ++it) {
      const int idx = it * 256 + tid;
      const int dhl = idx >> 4, c = idx & 15;
      u16x8 val = *(const u16x8*)&T[dhl * 136 + c * 8];
      *(u16x8*)&Vt[((size_t)(b * H_ + hb) * DH_ + dhl) * L_ + lbase + c * 8] = val;
    }
  }
}

// ---------------- causal flash attention ----------------
#define SCALE_ 0.08838834764831845f  // 1/sqrt(128)

__global__ __launch_bounds__(256, 2) void attn_kernel(
    const unsigned short* __restrict__ Qh, const unsigned short* __restrict__ Kh,
    const unsigned short* __restrict__ Vt, unsigned short* __restrict__ ctx) {
  __shared__ unsigned short Ks[64 * 128];   // [key][dh], chunk-swizzled
  __shared__ unsigned short Vs[128 * 64];   // [dh][key], chunk-swizzled
  __shared__ unsigned short Ps[4][16 * 64]; // per-wave P, chunk-swizzled

  const int qt = blockIdx.x, bh = blockIdx.y;
  const size_t hoff = (size_t)bh * L_ * DH_;
  const unsigned short* Qp = Qh + hoff;
  const unsigned short* Kp = Kh + hoff;
  const unsigned short* Vp = Vt + hoff;

  const int tid = threadIdx.x, wave = tid >> 6, lane = tid & 63;
  const int l15 = lane & 15, l4 = lane >> 4;

  // Q hoist: wave owns 16 q-rows; A-frag row = lane&15, k(dh) = s*32 + l4*8
  bf16x8 qf[4];
  {
    const int qrow = qt * 64 + wave * 16 + l15;
#pragma unroll
    for (int s = 0; s < 4; s++)
      qf[s] = *(const bf16x8*)&Qp[(size_t)qrow * DH_ + s * 32 + l4 * 8];
  }

  f32x4 o[8];
#pragma unroll
  for (int df = 0; df < 8; df++) { f32x4 zz = {0.f, 0.f, 0.f, 0.f}; o[df] = zz; }
  float m_r[4] = {-1e30f, -1e30f, -1e30f, -1e30f};
  float l_r[4] = {0.f, 0.f, 0.f, 0.f};

  for (int kt = 0; kt <= qt; ++kt) {
    // stage K tile [64][128]: slot s holds global chunk s^(r&7) (pre-swizzled source, linear LDS)
#pragma unroll
    for (int it = 0; it < 4; ++it) {
      const int base = it * 256 + wave * 64;
      const int ch = base + lane;
      const int r = ch >> 4, s = ch & 15;
      gld16(Kp + (size_t)(kt * 64 + r) * DH_ + ((s ^ (r & 7)) * 8), (unsigned short*)Ks + base * 8);
    }
    // stage V tile [128][64] from Vt rows
#pragma unroll
    for (int it = 0; it < 4; ++it) {
      const int base = it * 256 + wave * 64;
      const int ch = base + lane;
      const int r = ch >> 3, s = ch & 7;
      gld16(Vp + (size_t)r * L_ + kt * 64 + ((s ^ (r & 7)) * 8), (unsigned short*)Vs + base * 8);
    }
    __syncthreads();

    // S = Q K^T  (D-layout: row(q)=l4*4+j, col(key)=l15)
    f32x4 sa[4];
#pragma unroll
    for (int f = 0; f < 4; f++) { f32x4 zz = {0.f, 0.f, 0.f, 0.f}; sa[f] = zz; }
#pragma unroll
    for (int ks = 0; ks < 4; ++ks) {
#pragma unroll
      for (int f = 0; f < 4; ++f) {
        const int n = f * 16 + l15;
        const int c = ks * 4 + l4;
        bf16x8 kf = *(const bf16x8*)&Ks[n * 128 + ((c ^ (n & 7)) * 8)];
        sa[f] = __builtin_amdgcn_mfma_f32_16x16x32_bf16(qf[ks], kf, sa[f], 0, 0, 0);
      }
    }

    const bool diag = (kt == qt);
#pragma unroll
    for (int f = 0; f < 4; f++) {
      const int kg = f * 16 + l15;  // key within tile
#pragma unroll
      for (int j = 0; j < 4; j++) {
        float t = sa[f][j] * SCALE_;
        if (diag && kg > wave * 16 + l4 * 4 + j) t = -1e30f;
        sa[f][j] = t;
      }
    }

    // online softmax (rows live across the 16-lane subgroup)
    float pvv[4][4];
#pragma unroll
    for (int j = 0; j < 4; j++) {
      float mx = fmaxf(fmaxf(sa[0][j], sa[1][j]), fmaxf(sa[2][j], sa[3][j]));
#pragma unroll
      for (int d = 1; d < 16; d <<= 1) mx = fmaxf(mx, __shfl_xor(mx, d));
      const float mnew = fmaxf(m_r[j], mx);
      const float alpha = __expf(m_r[j] - mnew);
      float rs = 0.f;
#pragma unroll
      for (int f = 0; f < 4; f++) { float p = __expf(sa[f][j] - mnew); pvv[f][j] = p; rs += p; }
#pragma unroll
      for (int d = 1; d < 16; d <<= 1) rs += __shfl_xor(rs, d);
      l_r[j] = l_r[j] * alpha + rs;
      m_r[j] = mnew;
#pragma unroll
      for (int df = 0; df < 8; df++) o[df][j] *= alpha;
    }

    // P -> bf16 -> wave-private LDS (swizzled); converts D-layout to A-layout
#pragma unroll
    for (int f = 0; f < 4; f++)
#pragma unroll
      for (int j = 0; j < 4; j++) {
        const int row = l4 * 4 + j;
        const int col = f * 16 + l15;
        const int c = col >> 3;
        Ps[wave][row * 64 + ((c ^ (row & 7)) * 8) + (col & 7)] = f2bf(pvv[f][j]);
      }

    // O += P V
#pragma unroll
    for (int ks = 0; ks < 2; ++ks) {
      const int pc = ks * 4 + l4;
      bf16x8 pf = *(const bf16x8*)&Ps[wave][l15 * 64 + ((pc ^ (l15 & 7)) * 8)];
#pragma unroll
      for (int df = 0; df < 8; ++df) {
        const int vr = df * 16 + l15;
        bf16x8 vf = *(const bf16x8*)&Vs[vr * 64 + ((pc ^ (vr & 7)) * 8)];
        o[df] = __builtin_amdgcn_mfma_f32_16x16x32_bf16(pf, vf, o[df], 0, 0, 0);
      }
    }
    __syncthreads();
  }

  // normalize + write ctx[B,L,D] bf16
  const int b = bh >> 4, h = bh & 15;
#pragma unroll
  for (int j = 0; j < 4; j++) {
    const float inv = 1.0f / l_r[j];
    const int lq = qt * 64 + wave * 16 + l4 * 4 + j;
    const size_t rowb = ((size_t)(b * L_ + lq)) * D_ + h * DH_;
#pragma unroll
    for (int df = 0; df < 8; ++df)
      ctx[rowb + df * 16 + l15] = f2bf(o[df][j] * inv);
  }
}

// ---------------- output projection GEMM (f32 out) ----------------
__global__ __launch_bounds__(256, 2) void out_gemm(const unsigned short* __restrict__ ctx,
                                                   const unsigned short* __restrict__ wob,
                                                   float* __restrict__ out) {
  __shared__ unsigned short smem[2 * 128 * 64];
  unsigned short* As = smem;
  unsigned short* Bs = smem + 128 * 64;

  const int tid = threadIdx.x;
  const int wave = tid >> 6, lane = tid & 63;
  const int wr = wave >> 1, wc = wave & 1;
  const int bm0 = blockIdx.x * 128;
  const int bn0 = blockIdx.y * 128;
  const int l15 = lane & 15, l4 = lane >> 4;

  f32x4 acc[4][4];
#pragma unroll
  for (int m = 0; m < 4; m++)
#pragma unroll
    for (int n = 0; n < 4; n++) { f32x4 zz = {0.f, 0.f, 0.f, 0.f}; acc[m][n] = zz; }

  for (int k0 = 0; k0 < K_; k0 += 64) {
#pragma unroll
    for (int it = 0; it < 4; ++it) {
      const int base = it * 256 + wave * 64;
      const int ch = base + lane;
      const int r = ch >> 3, c = ch & 7;
      gld16(ctx + (size_t)(bm0 + r) * K_ + (k0 + c * 8), As + base * 8);
      gld16(wob + (size_t)(bn0 + r) * K_ + (k0 + c * 8), Bs + base * 8);
    }
    __syncthreads();
#pragma unroll
    for (int ks = 0; ks < 2; ++ks) {
      const int kc = ks * 32 + l4 * 8;
      bf16x8 af[4], bfr[4];
#pragma unroll
      for (int m = 0; m < 4; m++) af[m] = *(const bf16x8*)&As[(wr * 64 + m * 16 + l15) * 64 + kc];
#pragma unroll
      for (int n = 0; n < 4; n++) bfr[n] = *(const bf16x8*)&Bs[(wc * 64 + n * 16 + l15) * 64 + kc];
#pragma unroll
      for (int m = 0; m < 4; m++)
#pragma unroll
        for (int n = 0; n < 4; n++)
          acc[m][n] = __builtin_amdgcn_mfma_f32_16x16x32_bf16(af[m], bfr[n], acc[m][n], 0, 0, 0);
    }
    __syncthreads();
  }

#pragma unroll
  for (int m = 0; m < 4; m++) {
    const int rr = bm0 + wr * 64 + m * 16 + l4 * 4;
#pragma unroll
    for (int n = 0; n < 4; n++) {
      const int cc = bn0 + wc * 64 + n * 16 + l15;
#pragma unroll
      for (int j = 0; j < 4; j++) out[(size_t)(rr + j) * D_ + cc] = acc[m][n][j];
    }
  }
}

extern "C" void kernel_launch(void* const* d_in, const int* in_sizes, int n_in,
                              void* d_out, int out_size, void* d_ws, size_t ws_size,
                              hipStream_t stream) {
  const float* q  = (const float*)d_in[0];
  const float* k  = (const float*)d_in[1];
  const float* v  = (const float*)d_in[2];
  // d_in[3] = attn_mask: fixed causal triu(k=1); implemented analytically in-kernel
  const float* wq = (const float*)d_in[4];
  const float* wk = (const float*)d_in[5];
  const float* wv = (const float*)d_in[6];
  const float* wo = (const float*)d_in[7];

  const size_t DD = (size_t)D_ * D_;        // 4.19M
  const size_t BLD = (size_t)B_ * L_ * D_;  // 8.39M
  unsigned short* ws  = (unsigned short*)d_ws;
  unsigned short* wqb = ws;
  unsigned short* wkb = wqb + DD;
  unsigned short* wvb = wkb + DD;
  unsigned short* wob = wvb + DD;
  unsigned short* QhP = wob + DD;
  unsigned short* KhP = QhP + BLD;
  unsigned short* VtP = KhP + BLD;
  unsigned short* ctx = VtP + BLD;  // total ~100.7 MB of d_ws

  cvt_w<<<dim3(2048, 1, 4), 256, 0, stream>>>(wq, wk, wv, wo, ws);
  proj_gemm<<<dim3(32, 16, 3), 256, 0, stream>>>(q, k, v, wqb, wkb, wvb, QhP, KhP, VtP);
  attn_kernel<<<dim3(32, 32), 256, 0, stream>>>(QhP, KhP, VtP, ctx);
  out_gemm<<<dim3(32, 16), 256, 0, stream>>>(ctx, wob, (float*)d_out);
}

// Round 2
// 303.768 us; speedup vs baseline: 1.3047x; 1.3047x over previous
//
#include <hip/hip_runtime.h>

#define B_  2
#define L_  2048
#define D_  2048
#define H_  16
#define DH_ 128
#define K_  2048
#define M_  4096

typedef __attribute__((ext_vector_type(8))) short bf16x8;
typedef __attribute__((ext_vector_type(4))) float f32x4;
typedef __attribute__((ext_vector_type(4))) float float4v;
typedef __attribute__((ext_vector_type(8))) unsigned short u16x8;

__device__ __forceinline__ unsigned short f2bf(float f) {
  unsigned u = __builtin_bit_cast(unsigned, f);
  u += 0x7fffu + ((u >> 16) & 1u);
  return (unsigned short)(u >> 16);
}

typedef __attribute__((address_space(3))) unsigned int lds_uint;
typedef __attribute__((address_space(1))) const unsigned int glob_uint;
__device__ __forceinline__ void gld16(const void* g, void* l) {
  __builtin_amdgcn_global_load_lds((glob_uint*)g, (lds_uint*)l, 16, 0, 0);
}

// ---------------- f32 -> bf16 prepass (weights + activations) ----------------
__global__ void cvt_all(const float* __restrict__ wq, const float* __restrict__ wk,
                        const float* __restrict__ wv, const float* __restrict__ wo,
                        const float* __restrict__ q, const float* __restrict__ k,
                        const float* __restrict__ v, unsigned short* __restrict__ ws,
                        int nacts) {
  const size_t DD = (size_t)D_ * D_;
  const size_t BLD = (size_t)B_ * L_ * D_;
  const int z = blockIdx.z;
  const float* src;
  unsigned short* dst;
  size_t nelem;
  if (z < 4) {
    src = (z == 0) ? wq : (z == 1) ? wk : (z == 2) ? wv : wo;
    dst = ws + (size_t)z * DD;
    nelem = DD;
  } else {
    if (z - 4 >= nacts) return;
    src = (z == 4) ? q : (z == 5) ? k : v;
    dst = ws + 4 * DD + (size_t)(z - 4) * BLD;
    nelem = BLD;
  }
  size_t i = ((size_t)blockIdx.x * 256 + threadIdx.x) * 8;
  if (i >= nelem) return;
  float4v x0 = *(const float4v*)(src + i);
  float4v x1 = *(const float4v*)(src + i + 4);
  u16x8 p;
  p[0]=f2bf(x0[0]); p[1]=f2bf(x0[1]); p[2]=f2bf(x0[2]); p[3]=f2bf(x0[3]);
  p[4]=f2bf(x1[0]); p[5]=f2bf(x1[1]); p[6]=f2bf(x1[2]); p[7]=f2bf(x1[3]);
  *(u16x8*)(dst + i) = p;
}

// ---------------- fused QKV projection GEMM ----------------
// C[M,N] = A[M,K] * W_bf16[N,K]^T ; z=0 -> Qh[B,H,L,DH], z=1 -> Kh, z=2 -> Vt[B,H,DH,L]
// ABF16: A is bf16 (use global_load_lds); else A is f32 (reg-stage + cvt)
template <bool ABF16>
__global__ __launch_bounds__(256, 2) void proj_gemm(
    const void* __restrict__ a0, const void* __restrict__ a1, const void* __restrict__ a2,
    const unsigned short* __restrict__ wqb, const unsigned short* __restrict__ wkb,
    const unsigned short* __restrict__ wvb,
    unsigned short* __restrict__ Qh, unsigned short* __restrict__ Kh,
    unsigned short* __restrict__ Vt) {
  __shared__ unsigned short smem[128 * 136];  // staging: As[128][64]+Bs[128][64]; epi: T[128][136]
  unsigned short* As = smem;
  unsigned short* Bs = smem + 128 * 64;

  const int z = blockIdx.z;
  const void* A = (z == 0) ? a0 : (z == 1) ? a1 : a2;
  const unsigned short* W = (z == 0) ? wqb : (z == 1) ? wkb : wvb;

  const int tid = threadIdx.x;
  const int wave = tid >> 6, lane = tid & 63;
  const int wr = wave >> 1, wc = wave & 1;
  const int bm0 = blockIdx.x * 128;
  const int bn0 = blockIdx.y * 128;
  const int l15 = lane & 15, l4 = lane >> 4;

  f32x4 acc[4][4];
#pragma unroll
  for (int m = 0; m < 4; m++)
#pragma unroll
    for (int n = 0; n < 4; n++) { f32x4 zz = {0.f, 0.f, 0.f, 0.f}; acc[m][n] = zz; }

  for (int k0 = 0; k0 < K_; k0 += 64) {
#pragma unroll
    for (int it = 0; it < 4; ++it) {
      const int base = it * 256 + wave * 64;
      const int ch = base + lane;
      const int r = ch >> 3, c = ch & 7;
      gld16(W + (size_t)(bn0 + r) * K_ + (k0 + c * 8), Bs + base * 8);
    }
    if (ABF16) {
#pragma unroll
      for (int it = 0; it < 4; ++it) {
        const int base = it * 256 + wave * 64;
        const int ch = base + lane;
        const int r = ch >> 3, c = ch & 7;
        gld16((const unsigned short*)A + (size_t)(bm0 + r) * K_ + (k0 + c * 8), As + base * 8);
      }
    } else {
#pragma unroll
      for (int it = 0; it < 4; ++it) {
        const int ch = it * 256 + tid;
        const int r = ch >> 3, c = ch & 7;
        const float* g = (const float*)A + (size_t)(bm0 + r) * K_ + (k0 + c * 8);
        float4v x0 = *(const float4v*)g;
        float4v x1 = *(const float4v*)(g + 4);
        u16x8 p;
        p[0]=f2bf(x0[0]); p[1]=f2bf(x0[1]); p[2]=f2bf(x0[2]); p[3]=f2bf(x0[3]);
        p[4]=f2bf(x1[0]); p[5]=f2bf(x1[1]); p[6]=f2bf(x1[2]); p[7]=f2bf(x1[3]);
        *(u16x8*)&As[ch * 8] = p;
      }
    }
    __syncthreads();
#pragma unroll
    for (int ks = 0; ks < 2; ++ks) {
      const int kc = ks * 32 + l4 * 8;
      bf16x8 af[4], bfr[4];
#pragma unroll
      for (int m = 0; m < 4; m++) af[m] = *(const bf16x8*)&As[(wr * 64 + m * 16 + l15) * 64 + kc];
#pragma unroll
      for (int n = 0; n < 4; n++) bfr[n] = *(const bf16x8*)&Bs[(wc * 64 + n * 16 + l15) * 64 + kc];
#pragma unroll
      for (int m = 0; m < 4; m++)
#pragma unroll
        for (int n = 0; n < 4; n++)
          acc[m][n] = __builtin_amdgcn_mfma_f32_16x16x32_bf16(af[m], bfr[n], acc[m][n], 0, 0, 0);
    }
    __syncthreads();
  }

  if (z < 2) {
    unsigned short* O = (z == 0) ? Qh : Kh;
#pragma unroll
    for (int m = 0; m < 4; m++) {
      const int rr = bm0 + wr * 64 + m * 16 + l4 * 4;
#pragma unroll
      for (int n = 0; n < 4; n++) {
        const int cc = bn0 + wc * 64 + n * 16 + l15;
        const int h = cc >> 7, dh = cc & 127;
#pragma unroll
        for (int j = 0; j < 4; j++) {
          const int r2 = rr + j;
          const int b = r2 >> 11, lr = r2 & 2047;
          O[((size_t)(b * H_ + h) * L_ + lr) * DH_ + dh] = f2bf(acc[m][n][j]);
        }
      }
    }
  } else {
    // V: transpose through LDS, write Vt[B,H,DH,L] coalesced
    __syncthreads();
    unsigned short* T = smem;  // [128][136]
#pragma unroll
    for (int m = 0; m < 4; m++)
#pragma unroll
      for (int n = 0; n < 4; n++) {
        const int cl = wc * 64 + n * 16 + l15;
        const int rl = wr * 64 + m * 16 + l4 * 4;
#pragma unroll
        for (int j = 0; j < 4; j++) T[cl * 136 + rl + j] = f2bf(acc[m][n][j]);
      }
    __syncthreads();
    const int b = bm0 >> 11, lbase = bm0 & 2047;
    const int hb = bn0 >> 7;
#pragma unroll
    for (int it = 0; it < 8; ++it) {
      const int idx = it * 256 + tid;
      const int dhl = idx >> 4, c = idx & 15;
      u16x8 val = *(const u16x8*)&T[dhl * 136 + c * 8];
      *(u16x8*)&Vt[((size_t)(b * H_ + hb) * DH_ + dhl) * L_ + lbase + c * 8] = val;
    }
  }
}

// ---------------- causal flash attention ----------------
// QBLK=64 (4 waves x 16 q-rows), KVBLK=128. Block handles q-tiles {x, 31-x}:
// work = ceil((x+1)/2) + ceil((32-x)/2) = 17 KV-tiles for every block (balanced).
// Grid 512 blocks, 80KB LDS -> 2 blocks/CU -> all co-resident, no tail.
#define SCALE_ 0.08838834764831845f  // 1/sqrt(128)

__global__ __launch_bounds__(256, 2) void attn_kernel(
    const unsigned short* __restrict__ Qh, const unsigned short* __restrict__ Kh,
    const unsigned short* __restrict__ Vt, unsigned short* __restrict__ ctx) {
  __shared__ unsigned short Ks[128 * 128];   // [key][dh], chunk-swizzled
  __shared__ unsigned short Vs[128 * 128];   // [dh][key], chunk-swizzled
  __shared__ unsigned short Ps[4][16 * 128]; // per-wave P, chunk-swizzled

  const int pair = blockIdx.x, bh = blockIdx.y;
  const size_t hoff = (size_t)bh * L_ * DH_;
  const unsigned short* Qp = Qh + hoff;
  const unsigned short* Kp = Kh + hoff;
  const unsigned short* Vp = Vt + hoff;

  const int tid = threadIdx.x, wave = tid >> 6, lane = tid & 63;
  const int l15 = lane & 15, l4 = lane >> 4;
  const int b = bh >> 4, h = bh & 15;

#pragma unroll 1
  for (int p = 0; p < 2; ++p) {
    const int qt = p ? (31 - pair) : pair;
    const int ntiles = (qt + 2) >> 1;

    // Q hoist: wave owns 16 q-rows; A-frag row = lane&15, dh chunk = s*32 + l4*8
    bf16x8 qf[4];
    {
      const int qrow = qt * 64 + wave * 16 + l15;
#pragma unroll
      for (int s = 0; s < 4; s++)
        qf[s] = *(const bf16x8*)&Qp[(size_t)qrow * DH_ + s * 32 + l4 * 8];
    }

    f32x4 o[8];
#pragma unroll
    for (int df = 0; df < 8; df++) { f32x4 zz = {0.f, 0.f, 0.f, 0.f}; o[df] = zz; }
    float m_r[4] = {-1e30f, -1e30f, -1e30f, -1e30f};
    float l_r[4] = {0.f, 0.f, 0.f, 0.f};

    for (int kt = 0; kt < ntiles; ++kt) {
      // stage K tile [128][128]: LDS linear, source chunk pre-swizzled (G21)
#pragma unroll
      for (int it = 0; it < 8; ++it) {
        const int base = it * 256 + wave * 64;
        const int ch = base + lane;
        const int r = ch >> 4, s = ch & 15;
        gld16(Kp + (size_t)(kt * 128 + r) * DH_ + ((s ^ (r & 7)) * 8), (unsigned short*)Ks + base * 8);
      }
      // stage V tile [128 dh][128 key] from Vt rows
#pragma unroll
      for (int it = 0; it < 8; ++it) {
        const int base = it * 256 + wave * 64;
        const int ch = base + lane;
        const int r = ch >> 4, s = ch & 15;
        gld16(Vp + (size_t)r * L_ + kt * 128 + ((s ^ (r & 7)) * 8), (unsigned short*)Vs + base * 8);
      }
      __syncthreads();

      // S = Q K^T  (D-layout: row(q)=l4*4+j, col(key)=f*16+l15)
      f32x4 sa[8];
#pragma unroll
      for (int f = 0; f < 8; f++) { f32x4 zz = {0.f, 0.f, 0.f, 0.f}; sa[f] = zz; }
#pragma unroll
      for (int ks = 0; ks < 4; ++ks) {
        const int c = ks * 4 + l4;
#pragma unroll
        for (int f = 0; f < 8; ++f) {
          const int n = f * 16 + l15;
          bf16x8 kf = *(const bf16x8*)&Ks[n * 128 + ((c ^ (n & 7)) * 8)];
          sa[f] = __builtin_amdgcn_mfma_f32_16x16x32_bf16(qf[ks], kf, sa[f], 0, 0, 0);
        }
      }

      const bool last = (kt == ntiles - 1);
#pragma unroll
      for (int f = 0; f < 8; f++) {
        const int kg = kt * 128 + f * 16 + l15;
#pragma unroll
        for (int j = 0; j < 4; j++) {
          float t = sa[f][j] * SCALE_;
          if (last && kg > qt * 64 + wave * 16 + l4 * 4 + j) t = -1e30f;
          sa[f][j] = t;
        }
      }

      // online softmax (rows live across the 16-lane subgroup); fused P write
#pragma unroll
      for (int j = 0; j < 4; j++) {
        float mx = fmaxf(fmaxf(fmaxf(sa[0][j], sa[1][j]), fmaxf(sa[2][j], sa[3][j])),
                         fmaxf(fmaxf(sa[4][j], sa[5][j]), fmaxf(sa[6][j], sa[7][j])));
#pragma unroll
        for (int d = 1; d < 16; d <<= 1) mx = fmaxf(mx, __shfl_xor(mx, d));
        const float mnew = fmaxf(m_r[j], mx);
        const float alpha = __expf(m_r[j] - mnew);
        float rs = 0.f;
        const int row = l4 * 4 + j;
#pragma unroll
        for (int f = 0; f < 8; f++) {
          float pp = __expf(sa[f][j] - mnew);
          rs += pp;
          const int col = f * 16 + l15;
          const int c = col >> 3;
          Ps[wave][row * 128 + ((c ^ (row & 7)) * 8) + (col & 7)] = f2bf(pp);
        }
#pragma unroll
        for (int d = 1; d < 16; d <<= 1) rs += __shfl_xor(rs, d);
        l_r[j] = l_r[j] * alpha + rs;
        m_r[j] = mnew;
#pragma unroll
        for (int df = 0; df < 8; df++) o[df][j] *= alpha;
      }

      // O += P V
#pragma unroll
      for (int ksl = 0; ksl < 4; ++ksl) {
        const int pc = ksl * 4 + l4;
        bf16x8 pf = *(const bf16x8*)&Ps[wave][l15 * 128 + ((pc ^ (l15 & 7)) * 8)];
#pragma unroll
        for (int df = 0; df < 8; ++df) {
          const int vr = df * 16 + l15;
          bf16x8 vf = *(const bf16x8*)&Vs[vr * 128 + ((pc ^ (vr & 7)) * 8)];
          o[df] = __builtin_amdgcn_mfma_f32_16x16x32_bf16(pf, vf, o[df], 0, 0, 0);
        }
      }
      __syncthreads();
    }

    // normalize + write ctx[B,L,D] bf16
#pragma unroll
    for (int j = 0; j < 4; j++) {
      const float inv = 1.0f / l_r[j];
      const int lq = qt * 64 + wave * 16 + l4 * 4 + j;
      const size_t rowb = ((size_t)(b * L_ + lq)) * D_ + h * DH_;
#pragma unroll
      for (int df = 0; df < 8; ++df)
        ctx[rowb + df * 16 + l15] = f2bf(o[df][j] * inv);
    }
  }
}

// ---------------- output projection GEMM (f32 out) ----------------
__global__ __launch_bounds__(256, 2) void out_gemm(const unsigned short* __restrict__ ctx,
                                                   const unsigned short* __restrict__ wob,
                                                   float* __restrict__ out) {
  __shared__ unsigned short smem[2 * 128 * 64];
  unsigned short* As = smem;
  unsigned short* Bs = smem + 128 * 64;

  const int tid = threadIdx.x;
  const int wave = tid >> 6, lane = tid & 63;
  const int wr = wave >> 1, wc = wave & 1;
  const int bm0 = blockIdx.x * 128;
  const int bn0 = blockIdx.y * 128;
  const int l15 = lane & 15, l4 = lane >> 4;

  f32x4 acc[4][4];
#pragma unroll
  for (int m = 0; m < 4; m++)
#pragma unroll
    for (int n = 0; n < 4; n++) { f32x4 zz = {0.f, 0.f, 0.f, 0.f}; acc[m][n] = zz; }

  for (int k0 = 0; k0 < K_; k0 += 64) {
#pragma unroll
    for (int it = 0; it < 4; ++it) {
      const int base = it * 256 + wave * 64;
      const int ch = base + lane;
      const int r = ch >> 3, c = ch & 7;
      gld16(ctx + (size_t)(bm0 + r) * K_ + (k0 + c * 8), As + base * 8);
      gld16(wob + (size_t)(bn0 + r) * K_ + (k0 + c * 8), Bs + base * 8);
    }
    __syncthreads();
#pragma unroll
    for (int ks = 0; ks < 2; ++ks) {
      const int kc = ks * 32 + l4 * 8;
      bf16x8 af[4], bfr[4];
#pragma unroll
      for (int m = 0; m < 4; m++) af[m] = *(const bf16x8*)&As[(wr * 64 + m * 16 + l15) * 64 + kc];
#pragma unroll
      for (int n = 0; n < 4; n++) bfr[n] = *(const bf16x8*)&Bs[(wc * 64 + n * 16 + l15) * 64 + kc];
#pragma unroll
      for (int m = 0; m < 4; m++)
#pragma unroll
        for (int n = 0; n < 4; n++)
          acc[m][n] = __builtin_amdgcn_mfma_f32_16x16x32_bf16(af[m], bfr[n], acc[m][n], 0, 0, 0);
    }
    __syncthreads();
  }

#pragma unroll
  for (int m = 0; m < 4; m++) {
    const int rr = bm0 + wr * 64 + m * 16 + l4 * 4;
#pragma unroll
    for (int n = 0; n < 4; n++) {
      const int cc = bn0 + wc * 64 + n * 16 + l15;
#pragma unroll
      for (int j = 0; j < 4; j++) out[(size_t)(rr + j) * D_ + cc] = acc[m][n][j];
    }
  }
}

extern "C" void kernel_launch(void* const* d_in, const int* in_sizes, int n_in,
                              void* d_out, int out_size, void* d_ws, size_t ws_size,
                              hipStream_t stream) {
  const float* q  = (const float*)d_in[0];
  const float* k  = (const float*)d_in[1];
  const float* v  = (const float*)d_in[2];
  // d_in[3] = attn_mask: fixed causal triu(k=1); implemented analytically in-kernel
  const float* wq = (const float*)d_in[4];
  const float* wk = (const float*)d_in[5];
  const float* wv = (const float*)d_in[6];
  const float* wo = (const float*)d_in[7];

  const size_t DD = (size_t)D_ * D_;        // 4.19M
  const size_t BLD = (size_t)B_ * L_ * D_;  // 8.39M
  unsigned short* ws  = (unsigned short*)d_ws;
  unsigned short* wqb = ws;
  unsigned short* wkb = wqb + DD;
  unsigned short* wvb = wkb + DD;
  unsigned short* wob = wvb + DD;

  const size_t need_full = (4 * DD + 7 * BLD) * 2;  // ~151 MB

  if (ws_size >= need_full) {
    unsigned short* qb  = wob + DD;
    unsigned short* kb  = qb + BLD;
    unsigned short* vb  = kb + BLD;
    unsigned short* QhP = vb + BLD;
    unsigned short* KhP = QhP + BLD;
    unsigned short* VtP = KhP + BLD;
    unsigned short* ctx = VtP + BLD;

    cvt_all<<<dim3(4096, 1, 7), 256, 0, stream>>>(wq, wk, wv, wo, q, k, v, ws, 3);
    proj_gemm<true><<<dim3(32, 16, 3), 256, 0, stream>>>(qb, kb, vb, wqb, wkb, wvb, QhP, KhP, VtP);
    attn_kernel<<<dim3(16, 32), 256, 0, stream>>>(QhP, KhP, VtP, ctx);
    out_gemm<<<dim3(32, 16), 256, 0, stream>>>(ctx, wob, (float*)d_out);
  } else {
    unsigned short* QhP = wob + DD;
    unsigned short* KhP = QhP + BLD;
    unsigned short* VtP = KhP + BLD;
    unsigned short* ctx = VtP + BLD;

    cvt_all<<<dim3(4096, 1, 4), 256, 0, stream>>>(wq, wk, wv, wo, q, k, v, ws, 0);
    proj_gemm<false><<<dim3(32, 16, 3), 256, 0, stream>>>(q, k, v, wqb, wkb, wvb, QhP, KhP, VtP);
    attn_kernel<<<dim3(16, 32), 256, 0, stream>>>(QhP, KhP, VtP, ctx);
    out_gemm<<<dim3(32, 16), 256, 0, stream>>>(ctx, wob, (float*)d_out);
  }
}

// Round 3
// 291.293 us; speedup vs baseline: 1.3606x; 1.0428x over previous
//
#include <hip/hip_runtime.h>

#define B_  2
#define L_  2048
#define D_  2048
#define H_  16
#define DH_ 128
#define K_  2048

typedef __attribute__((ext_vector_type(8))) short bf16x8;
typedef __attribute__((ext_vector_type(4))) float f32x4;
typedef __attribute__((ext_vector_type(4))) float float4v;
typedef __attribute__((ext_vector_type(8))) unsigned short u16x8;
typedef __attribute__((ext_vector_type(4))) unsigned short u16x4;

__device__ __forceinline__ unsigned short f2bf(float f) {
  unsigned u = __builtin_bit_cast(unsigned, f);
  u += 0x7fffu + ((u >> 16) & 1u);
  return (unsigned short)(u >> 16);
}

typedef __attribute__((address_space(3))) unsigned int lds_uint;
typedef __attribute__((address_space(1))) const unsigned int glob_uint;
__device__ __forceinline__ void gld16(const void* g, void* l) {
  __builtin_amdgcn_global_load_lds((glob_uint*)g, (lds_uint*)l, 16, 0, 0);
}

#define BAR() do { asm volatile("" ::: "memory"); __builtin_amdgcn_s_barrier(); asm volatile("" ::: "memory"); } while (0)
#define VMCNT(n) asm volatile("s_waitcnt vmcnt(" #n ")" ::: "memory")

// ---------------- f32 -> bf16 prepass (weights + activations) ----------------
__global__ void cvt_all(const float* __restrict__ wq, const float* __restrict__ wk,
                        const float* __restrict__ wv, const float* __restrict__ wo,
                        const float* __restrict__ q, const float* __restrict__ k,
                        const float* __restrict__ v, unsigned short* __restrict__ ws,
                        int nacts) {
  const size_t DD = (size_t)D_ * D_;
  const size_t BLD = (size_t)B_ * L_ * D_;
  const int z = blockIdx.z;
  const float* src;
  unsigned short* dst;
  size_t nelem;
  if (z < 4) {
    src = (z == 0) ? wq : (z == 1) ? wk : (z == 2) ? wv : wo;
    dst = ws + (size_t)z * DD;
    nelem = DD;
  } else {
    if (z - 4 >= nacts) return;
    src = (z == 4) ? q : (z == 5) ? k : v;
    dst = ws + 4 * DD + (size_t)(z - 4) * BLD;
    nelem = BLD;
  }
  size_t i = ((size_t)blockIdx.x * 256 + threadIdx.x) * 8;
  if (i >= nelem) return;
  float4v x0 = *(const float4v*)(src + i);
  float4v x1 = *(const float4v*)(src + i + 4);
  u16x8 p;
  p[0]=f2bf(x0[0]); p[1]=f2bf(x0[1]); p[2]=f2bf(x0[2]); p[3]=f2bf(x0[3]);
  p[4]=f2bf(x1[0]); p[5]=f2bf(x1[1]); p[6]=f2bf(x1[2]); p[7]=f2bf(x1[3]);
  *(u16x8*)(dst + i) = p;
}

// ---------------- pipelined GEMM: BM=128 BN=256 BK=64, 8 waves, 3-deep LDS ring ----------------
// C[M,N] = A_bf16[M,K] * W_bf16[N,K]^T
// KIND=0: proj (grid z=3): z<2 -> head-major Qh/Kh bf16; z==2 -> Vt[B,H,DH,L] (LDS transpose)
// KIND=1: out projection -> f32 OF[M,N]
// Schedule per K-tile: 2 phases {ds_read frags | stage tile t+2 units | barrier |
//   setprio(1) 16 MFMA setprio(0) | barrier}, counted vmcnt(6) once per tile (T3+T4),
// chunk-XOR LDS swizzle on both staging source and reads (T2, G21), setprio (T5).
template <int KIND>
__global__ __launch_bounds__(512, 2) void gemm8(
    const unsigned short* __restrict__ a0, const unsigned short* __restrict__ a1,
    const unsigned short* __restrict__ a2,
    const unsigned short* __restrict__ w0, const unsigned short* __restrict__ w1,
    const unsigned short* __restrict__ w2,
    unsigned short* __restrict__ Qh, unsigned short* __restrict__ Kh,
    unsigned short* __restrict__ Vt, float* __restrict__ OF) {
  __shared__ unsigned short smem[3 * 24576];  // 3 bufs x (A 8192 + B 16384 shorts) = 144 KB

  // T1: bijective XCD swizzle (nwg = 768 / 256, both % 8 == 0)
  const int lin = blockIdx.x + 32 * (blockIdx.y + 8 * blockIdx.z);
  const int cpx = KIND ? 32 : 96;
  const int s = (lin & 7) * cpx + (lin >> 3);
  const int mt = s & 31;
  const int r_ = s >> 5;
  const int ntile = KIND ? r_ : (r_ & 7);
  const int z = KIND ? 0 : (r_ >> 3);

  const unsigned short* A = KIND ? a0 : (z == 0 ? a0 : z == 1 ? a1 : a2);
  const unsigned short* W = KIND ? w0 : (z == 0 ? w0 : z == 1 ? w1 : w2);
  const int mode = KIND ? 2 : (z == 2 ? 1 : 0);

  const int bm0 = mt * 128;
  const int bn0 = ntile * 256;

  const int tid = threadIdx.x;
  const int wid = tid >> 6, lane = tid & 63;
  const int wr = wid >> 2, wc = wid & 3;
  const int l15 = lane & 15, l4 = lane >> 4;

  // staging sources (pre-swizzled chunk, G21) + linear LDS dests; pointers bumped per stage
  const unsigned short* gsrc[6];
  int ldst[6];
  {
#pragma unroll
    for (int i = 0; i < 2; ++i) {
      const int c = i * 512 + tid, r = c >> 3, s0 = c & 7;
      gsrc[i] = A + (size_t)(bm0 + r) * K_ + ((s0 ^ (r & 7)) << 3);
      ldst[i] = c * 8;
    }
#pragma unroll
    for (int u = 0; u < 2; ++u)
#pragma unroll
      for (int i = 0; i < 2; ++i) {
        const int c = i * 512 + tid, r = c >> 3, s0 = c & 7;
        gsrc[2 + u * 2 + i] = W + (size_t)(bn0 + u * 128 + r) * K_ + ((s0 ^ (r & 7)) << 3);
        ldst[2 + u * 2 + i] = 8192 + (u * 1024 + c) * 8;
      }
  }
#define STAGE(idx, p) do { gld16(gsrc[idx], &smem[(p) * 24576 + ldst[idx]]); gsrc[idx] += 64; } while (0)

  // swizzled ds_read offsets (loop-invariant)
  int offA[2][2][2], offB[4][2];
#pragma unroll
  for (int mh = 0; mh < 2; ++mh)
#pragma unroll
    for (int ml = 0; ml < 2; ++ml)
#pragma unroll
      for (int ks = 0; ks < 2; ++ks) {
        const int row = wr * 64 + mh * 32 + ml * 16 + l15;
        const int ch = ks * 4 + l4;
        offA[mh][ml][ks] = row * 64 + ((ch ^ (row & 7)) << 3);
      }
#pragma unroll
  for (int nf = 0; nf < 4; ++nf)
#pragma unroll
    for (int ks = 0; ks < 2; ++ks) {
      const int rowb = wc * 64 + nf * 16 + l15;
      const int ch = ks * 4 + l4;
      offB[nf][ks] = 8192 + rowb * 64 + ((ch ^ (rowb & 7)) << 3);
    }

  f32x4 acc[4][4];
#pragma unroll
  for (int m = 0; m < 4; ++m)
#pragma unroll
    for (int n = 0; n < 4; ++n) { f32x4 zz = {0.f, 0.f, 0.f, 0.f}; acc[m][n] = zz; }

  // prologue: stage tiles 0,1; tile 0 guaranteed landed (vmcnt(6) leaves tile-1's 6 loads in flight)
  STAGE(0, 0); STAGE(1, 0); STAGE(2, 0); STAGE(3, 0); STAGE(4, 0); STAGE(5, 0);
  STAGE(0, 1); STAGE(1, 1); STAGE(2, 1); STAGE(3, 1); STAGE(4, 1); STAGE(5, 1);
  VMCNT(6);
  BAR();

  int p = 0;
  for (int t = 0; t < 32; ++t) {
    int p2 = p + 2; if (p2 >= 3) p2 -= 3;   // tile t+2 -> buffer of dead tile t-1
    const unsigned short* bA = &smem[p * 24576];
    bf16x8 af[2][2], bfr[4][2];
    // ---- phase 0: read A-low + all B; stage A(t+2), B0(t+2) ----
#pragma unroll
    for (int ml = 0; ml < 2; ++ml)
#pragma unroll
      for (int ks = 0; ks < 2; ++ks)
        af[ml][ks] = *(const bf16x8*)&bA[offA[0][ml][ks]];
#pragma unroll
    for (int nf = 0; nf < 4; ++nf)
#pragma unroll
      for (int ks = 0; ks < 2; ++ks)
        bfr[nf][ks] = *(const bf16x8*)&bA[offB[nf][ks]];
    if (t < 30) { STAGE(0, p2); STAGE(1, p2); STAGE(2, p2); STAGE(3, p2); }
    BAR();
    __builtin_amdgcn_s_setprio(1);
#pragma unroll
    for (int ml = 0; ml < 2; ++ml)
#pragma unroll
      for (int nf = 0; nf < 4; ++nf)
#pragma unroll
        for (int ks = 0; ks < 2; ++ks)
          acc[ml][nf] = __builtin_amdgcn_mfma_f32_16x16x32_bf16(af[ml][ks], bfr[nf][ks], acc[ml][nf], 0, 0, 0);
    __builtin_amdgcn_s_setprio(0);
    BAR();
    // ---- phase 1: read A-high (reuse B); stage B1(t+2); counted vmcnt ----
#pragma unroll
    for (int ml = 0; ml < 2; ++ml)
#pragma unroll
      for (int ks = 0; ks < 2; ++ks)
        af[ml][ks] = *(const bf16x8*)&bA[offA[1][ml][ks]];
    if (t < 30) { STAGE(4, p2); STAGE(5, p2); }
    BAR();
    __builtin_amdgcn_s_setprio(1);
#pragma unroll
    for (int ml = 0; ml < 2; ++ml)
#pragma unroll
      for (int nf = 0; nf < 4; ++nf)
#pragma unroll
        for (int ks = 0; ks < 2; ++ks)
          acc[2 + ml][nf] = __builtin_amdgcn_mfma_f32_16x16x32_bf16(af[ml][ks], bfr[nf][ks], acc[2 + ml][nf], 0, 0, 0);
    __builtin_amdgcn_s_setprio(0);
    if (t < 30) { VMCNT(6); } else { VMCNT(0); }
    BAR();
    p = (p == 2) ? 0 : p + 1;
  }
#undef STAGE

  if (mode == 0) {
    unsigned short* O = (z == 0) ? Qh : Kh;
#pragma unroll
    for (int mf = 0; mf < 4; ++mf) {
      const int rr = bm0 + wr * 64 + mf * 16 + l4 * 4;
#pragma unroll
      for (int nf = 0; nf < 4; ++nf) {
        const int cc = bn0 + wc * 64 + nf * 16 + l15;
        const int h = cc >> 7, dh = cc & 127;
#pragma unroll
        for (int j = 0; j < 4; ++j) {
          const int r2 = rr + j;
          O[((size_t)((r2 >> 11) * H_ + h) * L_ + (r2 & 2047)) * DH_ + dh] = f2bf(acc[mf][nf][j]);
        }
      }
    }
  } else if (mode == 1) {
    // V: transpose via LDS (reuse ring buffers; all reads retired at final barrier)
    unsigned short* T = smem;  // [256 n][128 m] bf16, chunk-swizzled
#pragma unroll
    for (int mf = 0; mf < 4; ++mf) {
      const int rl = wr * 64 + mf * 16 + l4 * 4;
#pragma unroll
      for (int nf = 0; nf < 4; ++nf) {
        const int cl = wc * 64 + nf * 16 + l15;
        u16x4 vv;
#pragma unroll
        for (int j = 0; j < 4; ++j) vv[j] = f2bf(acc[mf][nf][j]);
        *(u16x4*)&T[cl * 128 + (((rl >> 3) ^ (cl & 7)) << 3) + (rl & 7)] = vv;
      }
    }
    __syncthreads();
    const int b = bm0 >> 11, lbase = bm0 & 2047;
#pragma unroll
    for (int it = 0; it < 8; ++it) {
      const int idx = it * 512 + tid;
      const int rT = idx >> 4, sT = idx & 15;
      u16x8 val = *(const u16x8*)&T[rT * 128 + ((sT ^ (rT & 7)) << 3)];
      const int n = bn0 + rT, h = n >> 7, dh = n & 127;
      *(u16x8*)&Vt[((size_t)(b * H_ + h) * DH_ + dh) * L_ + lbase + sT * 8] = val;
    }
  } else {
#pragma unroll
    for (int mf = 0; mf < 4; ++mf) {
      const int rr = bm0 + wr * 64 + mf * 16 + l4 * 4;
#pragma unroll
      for (int nf = 0; nf < 4; ++nf) {
        const int cc = bn0 + wc * 64 + nf * 16 + l15;
#pragma unroll
        for (int j = 0; j < 4; ++j) OF[(size_t)(rr + j) * D_ + cc] = acc[mf][nf][j];
      }
    }
  }
}

// ---------------- fallback 128x128 proj GEMM (f32 A), only if ws too small ----------------
__global__ __launch_bounds__(256, 2) void proj_gemm_f32a(
    const float* __restrict__ q, const float* __restrict__ k, const float* __restrict__ v,
    const unsigned short* __restrict__ wqb, const unsigned short* __restrict__ wkb,
    const unsigned short* __restrict__ wvb,
    unsigned short* __restrict__ Qh, unsigned short* __restrict__ Kh,
    unsigned short* __restrict__ Vt) {
  __shared__ unsigned short smem[128 * 136];
  unsigned short* As = smem;
  unsigned short* Bs = smem + 128 * 64;

  const int z = blockIdx.z;
  const float* A = (z == 0) ? q : (z == 1) ? k : v;
  const unsigned short* W = (z == 0) ? wqb : (z == 1) ? wkb : wvb;

  const int tid = threadIdx.x;
  const int wave = tid >> 6, lane = tid & 63;
  const int wr = wave >> 1, wc = wave & 1;
  const int bm0 = blockIdx.x * 128;
  const int bn0 = blockIdx.y * 128;
  const int l15 = lane & 15, l4 = lane >> 4;

  f32x4 acc[4][4];
#pragma unroll
  for (int m = 0; m < 4; m++)
#pragma unroll
    for (int n = 0; n < 4; n++) { f32x4 zz = {0.f, 0.f, 0.f, 0.f}; acc[m][n] = zz; }

  for (int k0 = 0; k0 < K_; k0 += 64) {
#pragma unroll
    for (int it = 0; it < 4; ++it) {
      const int base = it * 256 + wave * 64;
      const int ch = base + lane;
      const int r = ch >> 3, c = ch & 7;
      gld16(W + (size_t)(bn0 + r) * K_ + (k0 + c * 8), Bs + base * 8);
    }
#pragma unroll
    for (int it = 0; it < 4; ++it) {
      const int ch = it * 256 + tid;
      const int r = ch >> 3, c = ch & 7;
      const float* g = A + (size_t)(bm0 + r) * K_ + (k0 + c * 8);
      float4v x0 = *(const float4v*)g;
      float4v x1 = *(const float4v*)(g + 4);
      u16x8 pp;
      pp[0]=f2bf(x0[0]); pp[1]=f2bf(x0[1]); pp[2]=f2bf(x0[2]); pp[3]=f2bf(x0[3]);
      pp[4]=f2bf(x1[0]); pp[5]=f2bf(x1[1]); pp[6]=f2bf(x1[2]); pp[7]=f2bf(x1[3]);
      *(u16x8*)&As[ch * 8] = pp;
    }
    __syncthreads();
#pragma unroll
    for (int ks = 0; ks < 2; ++ks) {
      const int kc = ks * 32 + l4 * 8;
      bf16x8 af[4], bfr[4];
#pragma unroll
      for (int m = 0; m < 4; m++) af[m] = *(const bf16x8*)&As[(wr * 64 + m * 16 + l15) * 64 + kc];
#pragma unroll
      for (int n = 0; n < 4; n++) bfr[n] = *(const bf16x8*)&Bs[(wc * 64 + n * 16 + l15) * 64 + kc];
#pragma unroll
      for (int m = 0; m < 4; m++)
#pragma unroll
        for (int n = 0; n < 4; n++)
          acc[m][n] = __builtin_amdgcn_mfma_f32_16x16x32_bf16(af[m], bfr[n], acc[m][n], 0, 0, 0);
    }
    __syncthreads();
  }

  if (z < 2) {
    unsigned short* O = (z == 0) ? Qh : Kh;
#pragma unroll
    for (int m = 0; m < 4; m++) {
      const int rr = bm0 + wr * 64 + m * 16 + l4 * 4;
#pragma unroll
      for (int n = 0; n < 4; n++) {
        const int cc = bn0 + wc * 64 + n * 16 + l15;
        const int h = cc >> 7, dh = cc & 127;
#pragma unroll
        for (int j = 0; j < 4; j++) {
          const int r2 = rr + j;
          O[((size_t)((r2 >> 11) * H_ + h) * L_ + (r2 & 2047)) * DH_ + dh] = f2bf(acc[m][n][j]);
        }
      }
    }
  } else {
    __syncthreads();
    unsigned short* T = smem;  // [128][136]
#pragma unroll
    for (int m = 0; m < 4; m++)
#pragma unroll
      for (int n = 0; n < 4; n++) {
        const int cl = wc * 64 + n * 16 + l15;
        const int rl = wr * 64 + m * 16 + l4 * 4;
#pragma unroll
        for (int j = 0; j < 4; j++) T[cl * 136 + rl + j] = f2bf(acc[m][n][j]);
      }
    __syncthreads();
    const int b = bm0 >> 11, lbase = bm0 & 2047;
    const int hb = bn0 >> 7;
#pragma unroll
    for (int it = 0; it < 8; ++it) {
      const int idx = it * 256 + tid;
      const int dhl = idx >> 4, c = idx & 15;
      u16x8 val = *(const u16x8*)&T[dhl * 136 + c * 8];
      *(u16x8*)&Vt[((size_t)(b * H_ + hb) * DH_ + dhl) * L_ + lbase + c * 8] = val;
    }
  }
}

// ---------------- causal flash attention ----------------
#define SCALE_ 0.08838834764831845f  // 1/sqrt(128)

__global__ __launch_bounds__(256, 2) void attn_kernel(
    const unsigned short* __restrict__ Qh, const unsigned short* __restrict__ Kh,
    const unsigned short* __restrict__ Vt, unsigned short* __restrict__ ctx) {
  __shared__ unsigned short Ks[128 * 128];   // [key][dh], chunk-swizzled
  __shared__ unsigned short Vs[128 * 128];   // [dh][key], chunk-swizzled
  __shared__ unsigned short Ps[4][16 * 128]; // per-wave P, chunk-swizzled

  const int pair = blockIdx.x, bh = blockIdx.y;
  const size_t hoff = (size_t)bh * L_ * DH_;
  const unsigned short* Qp = Qh + hoff;
  const unsigned short* Kp = Kh + hoff;
  const unsigned short* Vp = Vt + hoff;

  const int tid = threadIdx.x, wave = tid >> 6, lane = tid & 63;
  const int l15 = lane & 15, l4 = lane >> 4;
  const int b = bh >> 4, h = bh & 15;

#pragma unroll 1
  for (int p = 0; p < 2; ++p) {
    const int qt = p ? (31 - pair) : pair;
    const int ntiles = (qt + 2) >> 1;

    bf16x8 qf[4];
    {
      const int qrow = qt * 64 + wave * 16 + l15;
#pragma unroll
      for (int s = 0; s < 4; s++)
        qf[s] = *(const bf16x8*)&Qp[(size_t)qrow * DH_ + s * 32 + l4 * 8];
    }

    f32x4 o[8];
#pragma unroll
    for (int df = 0; df < 8; df++) { f32x4 zz = {0.f, 0.f, 0.f, 0.f}; o[df] = zz; }
    float m_r[4] = {-1e30f, -1e30f, -1e30f, -1e30f};
    float l_r[4] = {0.f, 0.f, 0.f, 0.f};

    for (int kt = 0; kt < ntiles; ++kt) {
#pragma unroll
      for (int it = 0; it < 8; ++it) {
        const int base = it * 256 + wave * 64;
        const int ch = base + lane;
        const int r = ch >> 4, s = ch & 15;
        gld16(Kp + (size_t)(kt * 128 + r) * DH_ + ((s ^ (r & 7)) * 8), (unsigned short*)Ks + base * 8);
      }
#pragma unroll
      for (int it = 0; it < 8; ++it) {
        const int base = it * 256 + wave * 64;
        const int ch = base + lane;
        const int r = ch >> 4, s = ch & 15;
        gld16(Vp + (size_t)r * L_ + kt * 128 + ((s ^ (r & 7)) * 8), (unsigned short*)Vs + base * 8);
      }
      __syncthreads();

      f32x4 sa[8];
#pragma unroll
      for (int f = 0; f < 8; f++) { f32x4 zz = {0.f, 0.f, 0.f, 0.f}; sa[f] = zz; }
      __builtin_amdgcn_s_setprio(1);
#pragma unroll
      for (int ks = 0; ks < 4; ++ks) {
        const int c = ks * 4 + l4;
#pragma unroll
        for (int f = 0; f < 8; ++f) {
          const int n = f * 16 + l15;
          bf16x8 kf = *(const bf16x8*)&Ks[n * 128 + ((c ^ (n & 7)) * 8)];
          sa[f] = __builtin_amdgcn_mfma_f32_16x16x32_bf16(qf[ks], kf, sa[f], 0, 0, 0);
        }
      }
      __builtin_amdgcn_s_setprio(0);

      const bool last = (kt == ntiles - 1);
#pragma unroll
      for (int f = 0; f < 8; f++) {
        const int kg = kt * 128 + f * 16 + l15;
#pragma unroll
        for (int j = 0; j < 4; j++) {
          float t = sa[f][j] * SCALE_;
          if (last && kg > qt * 64 + wave * 16 + l4 * 4 + j) t = -1e30f;
          sa[f][j] = t;
        }
      }

#pragma unroll
      for (int j = 0; j < 4; j++) {
        float mx = fmaxf(fmaxf(fmaxf(sa[0][j], sa[1][j]), fmaxf(sa[2][j], sa[3][j])),
                         fmaxf(fmaxf(sa[4][j], sa[5][j]), fmaxf(sa[6][j], sa[7][j])));
#pragma unroll
        for (int d = 1; d < 16; d <<= 1) mx = fmaxf(mx, __shfl_xor(mx, d));
        const float mnew = fmaxf(m_r[j], mx);
        const float alpha = __expf(m_r[j] - mnew);
        float rs = 0.f;
        const int row = l4 * 4 + j;
#pragma unroll
        for (int f = 0; f < 8; f++) {
          float pp = __expf(sa[f][j] - mnew);
          rs += pp;
          const int col = f * 16 + l15;
          const int c = col >> 3;
          Ps[wave][row * 128 + ((c ^ (row & 7)) * 8) + (col & 7)] = f2bf(pp);
        }
#pragma unroll
        for (int d = 1; d < 16; d <<= 1) rs += __shfl_xor(rs, d);
        l_r[j] = l_r[j] * alpha + rs;
        m_r[j] = mnew;
#pragma unroll
        for (int df = 0; df < 8; df++) o[df][j] *= alpha;
      }

      __builtin_amdgcn_s_setprio(1);
#pragma unroll
      for (int ksl = 0; ksl < 4; ++ksl) {
        const int pc = ksl * 4 + l4;
        bf16x8 pf = *(const bf16x8*)&Ps[wave][l15 * 128 + ((pc ^ (l15 & 7)) * 8)];
#pragma unroll
        for (int df = 0; df < 8; ++df) {
          const int vr = df * 16 + l15;
          bf16x8 vf = *(const bf16x8*)&Vs[vr * 128 + ((pc ^ (vr & 7)) * 8)];
          o[df] = __builtin_amdgcn_mfma_f32_16x16x32_bf16(pf, vf, o[df], 0, 0, 0);
        }
      }
      __builtin_amdgcn_s_setprio(0);
      __syncthreads();
    }

#pragma unroll
    for (int j = 0; j < 4; j++) {
      const float inv = 1.0f / l_r[j];
      const int lq = qt * 64 + wave * 16 + l4 * 4 + j;
      const size_t rowb = ((size_t)(b * L_ + lq)) * D_ + h * DH_;
#pragma unroll
      for (int df = 0; df < 8; ++df)
        ctx[rowb + df * 16 + l15] = f2bf(o[df][j] * inv);
    }
  }
}

extern "C" void kernel_launch(void* const* d_in, const int* in_sizes, int n_in,
                              void* d_out, int out_size, void* d_ws, size_t ws_size,
                              hipStream_t stream) {
  const float* q  = (const float*)d_in[0];
  const float* k  = (const float*)d_in[1];
  const float* v  = (const float*)d_in[2];
  // d_in[3] = attn_mask: fixed causal triu(k=1); implemented analytically in-kernel
  const float* wq = (const float*)d_in[4];
  const float* wk = (const float*)d_in[5];
  const float* wv = (const float*)d_in[6];
  const float* wo = (const float*)d_in[7];

  const size_t DD = (size_t)D_ * D_;
  const size_t BLD = (size_t)B_ * L_ * D_;
  unsigned short* ws  = (unsigned short*)d_ws;
  unsigned short* wqb = ws;
  unsigned short* wkb = wqb + DD;
  unsigned short* wvb = wkb + DD;
  unsigned short* wob = wvb + DD;

  const size_t need_full = (4 * DD + 7 * BLD) * 2;  // ~151 MB

  if (ws_size >= need_full) {
    unsigned short* qb  = wob + DD;
    unsigned short* kb  = qb + BLD;
    unsigned short* vb  = kb + BLD;
    unsigned short* QhP = vb + BLD;
    unsigned short* KhP = QhP + BLD;
    unsigned short* VtP = KhP + BLD;
    unsigned short* ctx = VtP + BLD;

    cvt_all<<<dim3(4096, 1, 7), 256, 0, stream>>>(wq, wk, wv, wo, q, k, v, ws, 3);
    gemm8<0><<<dim3(32, 8, 3), 512, 0, stream>>>(qb, kb, vb, wqb, wkb, wvb, QhP, KhP, VtP, nullptr);
    attn_kernel<<<dim3(16, 32), 256, 0, stream>>>(QhP, KhP, VtP, ctx);
    gemm8<1><<<dim3(32, 8, 1), 512, 0, stream>>>(ctx, nullptr, nullptr, wob, nullptr, nullptr,
                                                 nullptr, nullptr, nullptr, (float*)d_out);
  } else {
    unsigned short* QhP = wob + DD;
    unsigned short* KhP = QhP + BLD;
    unsigned short* VtP = KhP + BLD;
    unsigned short* ctx = VtP + BLD;

    cvt_all<<<dim3(4096, 1, 4), 256, 0, stream>>>(wq, wk, wv, wo, q, k, v, ws, 0);
    proj_gemm_f32a<<<dim3(32, 16, 3), 256, 0, stream>>>(q, k, v, wqb, wkb, wvb, QhP, KhP, VtP);
    attn_kernel<<<dim3(16, 32), 256, 0, stream>>>(QhP, KhP, VtP, ctx);
    gemm8<1><<<dim3(32, 8, 1), 512, 0, stream>>>(ctx, nullptr, nullptr, wob, nullptr, nullptr,
                                                 nullptr, nullptr, nullptr, (float*)d_out);
  }
}